// Round 10
// baseline (428.009 us; speedup 1.0000x reference)
//
#include <hip/hip_runtime.h>
#include <hip/hip_fp16.h>
#include <math.h>

typedef _Float16 f16;
typedef __attribute__((ext_vector_type(4))) _Float16 f16x4;
typedef __attribute__((ext_vector_type(8))) _Float16 f16x8;
typedef __attribute__((ext_vector_type(4))) float f32x4;

static constexpr int NBATCH = 4, DK = 128, DV = 512, L = 4096;
static constexpr float PSCALE = 256.f; // fallback path only

__device__ __forceinline__ void async16(const void* g, void* l) {
  __builtin_amdgcn_global_load_lds((const __attribute__((address_space(1))) void*)g,
                                   (__attribute__((address_space(3))) void*)l, 16, 0, 0);
}

// combined input transposes: z<4 -> q_k batch z, z>=4 -> m_k batch z-4
// [DK][L] f32 -> [L][DK] f16
__global__ void k_tr2(const float* __restrict__ qk, const float* __restrict__ mk,
                      f16* __restrict__ qkT, f16* __restrict__ mkT) {
  __shared__ float tile[32][33];
  const int z = blockIdx.z;
  const size_t bs = (size_t)DK * L;
  const float* inb = (z < 4 ? qk : mk) + (size_t)(z & 3) * bs;
  f16* outb = (z < 4 ? qkT : mkT) + (size_t)(z & 3) * bs;
  const int c0 = blockIdx.x * 32, r0 = blockIdx.y * 32;
  const int tx = threadIdx.x, ty = threadIdx.y;
#pragma unroll
  for (int i = 0; i < 32; i += 8)
    tile[ty + i][tx] = inb[(size_t)(r0 + ty + i) * L + (c0 + tx)];
  __syncthreads();
#pragma unroll
  for (int i = 0; i < 32; i += 8)
    outb[(size_t)(c0 + ty + i) * DK + (r0 + tx)] = (f16)tile[tx][ty + i];
}

__global__ void k_cvt_f16(const float4* __restrict__ in, f16x4* __restrict__ out, int n4) {
  int i = blockIdx.x * blockDim.x + threadIdx.x;
  const int st = gridDim.x * blockDim.x;
  for (; i < n4; i += st) {
    float4 v = in[i];
    f16x4 o;
    o.x = (f16)v.x; o.y = (f16)v.y; o.z = (f16)v.z; o.w = (f16)v.w;
    out[i] = o;
  }
}

// QK: e'[z][q][m] = exp(oscale * sum_k qkT[z][q][k]*mkT[z][m][k]) (f16 out)
// + per-block row expsum partials (no-max softmax). R5-proven structure:
// 128x128 tile, BK=64, 4 waves, global_load_lds + XOR-source-swizzle.
__global__ __launch_bounds__(256, 2)
void k_qk(const f16* __restrict__ A, const f16* __restrict__ B,
          f16* __restrict__ C, float* __restrict__ aux, float oscale) {
  constexpr int BK = 64;
  const int M = L, N = L, K = DK;
  __shared__ __align__(16) f16 As[128 * BK];
  __shared__ __align__(16) f16 Bs[128 * BK];
  __shared__ float sums[128];
  const int z = blockIdx.z;
  int bx = blockIdx.x, by = blockIdx.y;
  {
    const int n = gridDim.x * gridDim.y;
    const int id = bx + gridDim.x * by;
    const int id2 = (id & 7) * (n >> 3) + (id >> 3); // XCD chunk (n%8==0)
    bx = id2 % gridDim.x;
    by = id2 / gridDim.x;
  }
  const f16* Ab = A + (size_t)z * M * K;
  const f16* Bbp = B + (size_t)z * N * K;
  const int row0 = by * 128, col0 = bx * 128;
  const int tid = threadIdx.x, lane = tid & 63, wv = tid >> 6;
  const int wr = wv >> 1, wc = wv & 1;
  f32x4 acc[4][4] = {};
  const int srow = wv * 32 + (lane >> 3);
  const int sc = (lane & 7) ^ (lane >> 3); // source chunk pre-swizzle
  const f16* aSrc = Ab + (size_t)(row0 + srow) * K + sc * 8;
  const f16* bSrc = Bbp + (size_t)(col0 + srow) * K + sc * 8;
  f16* aDst = &As[(wv * 32) * BK];
  f16* bDst = &Bs[(wv * 32) * BK];

  for (int k0 = 0; k0 < K; k0 += BK) {
    __syncthreads();
#pragma unroll
    for (int j = 0; j < 4; ++j) {
      async16(aSrc + (size_t)(j * 8) * K + k0, aDst + (j * 8) * BK);
      async16(bSrc + (size_t)(j * 8) * K + k0, bDst + (j * 8) * BK);
    }
    __syncthreads();
#pragma unroll
    for (int kk = 0; kk < BK / 32; ++kk) {
      const int cx = ((kk * 4 + (lane >> 4)) ^ (lane & 7)) * 8;
      f16x8 av[4], bv[4];
#pragma unroll
      for (int i = 0; i < 4; ++i) {
        av[i] = *(const f16x8*)&As[(wr * 64 + i * 16 + (lane & 15)) * BK + cx];
        bv[i] = *(const f16x8*)&Bs[(wc * 64 + i * 16 + (lane & 15)) * BK + cx];
      }
#pragma unroll
      for (int i = 0; i < 4; ++i)
#pragma unroll
        for (int j = 0; j < 4; ++j)
          acc[i][j] = __builtin_amdgcn_mfma_f32_16x16x32_f16(av[i], bv[j], acc[i][j], 0, 0, 0);
    }
  }
  // C/D layout: col = lane&15, row = (lane>>4)*4 + t
  const size_t cb = (size_t)z * M * N;
  const int er = (lane >> 4) * 4, ec = lane & 15;
  float rp[16];
#pragma unroll
  for (int u = 0; u < 16; ++u) rp[u] = 0.f;
#pragma unroll
  for (int i = 0; i < 4; ++i) {
    const int r = row0 + wr * 64 + i * 16 + er;
#pragma unroll
    for (int j = 0; j < 4; ++j) {
      const int c = col0 + wc * 64 + j * 16 + ec;
#pragma unroll
      for (int t = 0; t < 4; ++t) {
        const float e = __expf(acc[i][j][t] * oscale);
        C[cb + (size_t)(r + t) * N + c] = (f16)e;
        rp[i * 4 + t] += e;
      }
    }
  }
#pragma unroll
  for (int u = 0; u < 16; ++u) {
    rp[u] += __shfl_xor(rp[u], 1);
    rp[u] += __shfl_xor(rp[u], 2);
    rp[u] += __shfl_xor(rp[u], 4);
    rp[u] += __shfl_xor(rp[u], 8);
  }
  // combine the two col-waves (wc): exactly 2 addends -> deterministic
  if (wc == 1 && (lane & 15) == 0) {
#pragma unroll
    for (int i = 0; i < 4; ++i)
#pragma unroll
      for (int t = 0; t < 4; ++t)
        sums[wr * 64 + i * 16 + (lane >> 4) * 4 + t] = rp[i * 4 + t];
  }
  __syncthreads();
  if (wc == 0 && (lane & 15) == 0) {
#pragma unroll
    for (int i = 0; i < 4; ++i)
#pragma unroll
      for (int t = 0; t < 4; ++t) {
        const int r = wr * 64 + i * 16 + (lane >> 4) * 4 + t;
        aux[((size_t)z * gridDim.x + bx) * L + row0 + r] = rp[i * 4 + t] + sums[r];
      }
  }
}

// PV: barrier-free, LDS-free. mem[z][v][q] = rowinv[q]*sum_m mv[v][m]*e'[q][m]
// + fused p[z][m][q] = e'[q][m]*rowinv[q] writeback (block v_b owns m-quarter).
// Grid 1024 flat: id&7 = XCD; 4 v-blocks of one (q,z) co-XCD (e' L2-shared).
// Wave owns 32v x 64q; per 32-K step: 6 fragment-gather loads (16x64B
// zero-waste segments) + 8 MFMA. Latency hidden by TLP (no lockstep).
__global__ __launch_bounds__(256, 4)
void k_pv(const f16* __restrict__ mvh, const f16* __restrict__ E,
          const float* __restrict__ partial, float* __restrict__ memOut,
          float* __restrict__ P) {
  const int id = blockIdx.x;          // 0..1023
  const int c = id & 7, r = id >> 3;
  const int v_b = r & 3, s = r >> 2;  // s 0..31
  const int qz = c * 32 + s;          // 0..255 bijective
  const int z = qz >> 6, qb = qz & 63;
  const int q0 = qb * 64, v0 = v_b * 128;
  const int tid = threadIdx.x, lane = tid & 63, wv = tid >> 6;
  const int ri = lane & 15, oc = lane >> 4;
  const size_t LL = (size_t)L * L;

  // rowinv for q0+lane: bx-ascending sum (bit-identical to k_rowsum order)
  float ssum = 0.f;
  {
    const float* pp_ = partial + (size_t)z * 32 * L + q0 + lane;
#pragma unroll
    for (int b = 0; b < 32; ++b) ssum += pp_[(size_t)b * L];
  }
  const float inv = 1.f / ssum;
  float rv[4];
#pragma unroll
  for (int f = 0; f < 4; ++f) rv[f] = __shfl(inv, f * 16 + ri);
  const float rvw = __shfl(inv, wv * 16 + ri); // for p-writeback (frag wv)

  // fragment base pointers (row-major, K contiguous)
  const f16* ap0 = mvh + (size_t)z * DV * L + (size_t)(v0 + wv * 32 + ri) * L + oc * 8;
  const f16* ap1 = ap0 + (size_t)16 * L;
  const f16* bp0 = E + (size_t)z * LL + (size_t)(q0 + ri) * L + oc * 8;
  const f16* bp1 = bp0 + (size_t)16 * L;
  const f16* bp2 = bp0 + (size_t)32 * L;
  const f16* bp3 = bp0 + (size_t)48 * L;
  float* pw = P + (size_t)z * LL + q0 + wv * 16 + ri;

  f32x4 acc[2][4] = {};
#pragma unroll 2
  for (int k0 = 0; k0 < L; k0 += 32) {
    const f16x8 a0 = *(const f16x8*)(ap0 + k0);
    const f16x8 a1 = *(const f16x8*)(ap1 + k0);
    const f16x8 b0 = *(const f16x8*)(bp0 + k0);
    const f16x8 b1 = *(const f16x8*)(bp1 + k0);
    const f16x8 b2 = *(const f16x8*)(bp2 + k0);
    const f16x8 b3 = *(const f16x8*)(bp3 + k0);
    acc[0][0] = __builtin_amdgcn_mfma_f32_16x16x32_f16(a0, b0, acc[0][0], 0, 0, 0);
    acc[0][1] = __builtin_amdgcn_mfma_f32_16x16x32_f16(a0, b1, acc[0][1], 0, 0, 0);
    acc[0][2] = __builtin_amdgcn_mfma_f32_16x16x32_f16(a0, b2, acc[0][2], 0, 0, 0);
    acc[0][3] = __builtin_amdgcn_mfma_f32_16x16x32_f16(a0, b3, acc[0][3], 0, 0, 0);
    acc[1][0] = __builtin_amdgcn_mfma_f32_16x16x32_f16(a1, b0, acc[1][0], 0, 0, 0);
    acc[1][1] = __builtin_amdgcn_mfma_f32_16x16x32_f16(a1, b1, acc[1][1], 0, 0, 0);
    acc[1][2] = __builtin_amdgcn_mfma_f32_16x16x32_f16(a1, b2, acc[1][2], 0, 0, 0);
    acc[1][3] = __builtin_amdgcn_mfma_f32_16x16x32_f16(a1, b3, acc[1][3], 0, 0, 0);
    if ((k0 >> 10) == v_b) {
      // p-writeback from B-frag wv (wave-uniform select, no reg indexing)
      f16x8 bw;
      if (wv == 0)      bw = b0;
      else if (wv == 1) bw = b1;
      else if (wv == 2) bw = b2;
      else              bw = b3;
      float* pr = pw + (size_t)(k0 + oc * 8) * L;
#pragma unroll
      for (int j = 0; j < 8; ++j)
        __builtin_nontemporal_store((float)bw[j] * rvw, pr + (size_t)j * L);
    }
  }
  // mem epilogue: C row = v (A dim), col = q (B dim); col=lane&15, row=oc*4+t
  float* mob = memOut + (size_t)z * DV * L;
#pragma unroll
  for (int a = 0; a < 2; ++a) {
#pragma unroll
    for (int f = 0; f < 4; ++f) {
#pragma unroll
      for (int t = 0; t < 4; ++t) {
        const int v = v0 + wv * 32 + a * 16 + oc * 4 + t;
        const int q = q0 + f * 16 + ri;
        __builtin_nontemporal_store(acc[a][f][t] * rv[f],
                                    mob + (size_t)v * L + q);
      }
    }
  }
}

// ---------------- fallback-path kernels (proven round-1) ----------------
template<bool OUT_F16>
__global__ __launch_bounds__(256, 2)
void k_gemm_bt(const f16* __restrict__ A, const f16* __restrict__ B,
               void* __restrict__ C, int M, int N, int K, float oscale) {
  constexpr int BK = 64;
  __shared__ __align__(16) f16 As[128 * BK];
  __shared__ __align__(16) f16 Bs[128 * BK];
  const int z = blockIdx.z;
  const f16* Ab = A + (size_t)z * M * K;
  const f16* Bbp = B + (size_t)z * N * K;
  const int row0 = blockIdx.y * 128, col0 = blockIdx.x * 128;
  const int tid = threadIdx.x, lane = tid & 63, wv = tid >> 6;
  const int wr = wv >> 1, wc = wv & 1;
  f32x4 acc[4][4] = {};
  const int srow = wv * 32 + (lane >> 3);
  const int sc = (lane & 7) ^ (lane >> 3);
  const f16* aSrc = Ab + (size_t)(row0 + srow) * K + sc * 8;
  const f16* bSrc = Bbp + (size_t)(col0 + srow) * K + sc * 8;
  f16* aDst = &As[(wv * 32) * BK];
  f16* bDst = &Bs[(wv * 32) * BK];
  for (int k0 = 0; k0 < K; k0 += BK) {
    __syncthreads();
#pragma unroll
    for (int j = 0; j < 4; ++j) {
      async16(aSrc + (size_t)(j * 8) * K + k0, aDst + (j * 8) * BK);
      async16(bSrc + (size_t)(j * 8) * K + k0, bDst + (j * 8) * BK);
    }
    __syncthreads();
#pragma unroll
    for (int kk = 0; kk < BK / 32; ++kk) {
      const int cx = ((kk * 4 + (lane >> 4)) ^ (lane & 7)) * 8;
      f16x8 av[4], bv[4];
#pragma unroll
      for (int i = 0; i < 4; ++i) {
        av[i] = *(const f16x8*)&As[(wr * 64 + i * 16 + (lane & 15)) * BK + cx];
        bv[i] = *(const f16x8*)&Bs[(wc * 64 + i * 16 + (lane & 15)) * BK + cx];
      }
#pragma unroll
      for (int i = 0; i < 4; ++i)
#pragma unroll
        for (int j = 0; j < 4; ++j)
          acc[i][j] = __builtin_amdgcn_mfma_f32_16x16x32_f16(av[i], bv[j], acc[i][j], 0, 0, 0);
    }
  }
  const size_t cb = (size_t)z * M * N;
  const int er = (lane >> 4) * 4, ec = lane & 15;
#pragma unroll
  for (int i = 0; i < 4; ++i) {
    const int r = row0 + wr * 64 + i * 16 + er;
#pragma unroll
    for (int j = 0; j < 4; ++j) {
      const int c = col0 + wc * 64 + j * 16 + ec;
#pragma unroll
      for (int t = 0; t < 4; ++t) {
        const float v = acc[i][j][t] * oscale;
        if (OUT_F16) ((f16*)C)[cb + (size_t)(r + t) * N + c] = (f16)v;
        else        ((float*)C)[cb + (size_t)(r + t) * N + c] = v;
      }
    }
  }
}

__global__ __launch_bounds__(256)
void k_softmax(f16* __restrict__ S) {
  const size_t rowbase = (size_t)blockIdx.x * L;
  const int tid = threadIdx.x, ln = tid & 63, wv = tid >> 6;
  f16* p = S + rowbase + tid * 16;
  f16x8 v0 = *(const f16x8*)p;
  f16x8 v1 = *(const f16x8*)(p + 8);
  float x[16];
#pragma unroll
  for (int j = 0; j < 8; ++j) { x[j] = (float)v0[j]; x[8 + j] = (float)v1[j]; }
  float m = -3.0e38f;
#pragma unroll
  for (int j = 0; j < 16; ++j) m = fmaxf(m, x[j]);
#pragma unroll
  for (int off = 1; off < 64; off <<= 1) m = fmaxf(m, __shfl_xor(m, off));
  __shared__ float redm[4], reds[4];
  if (ln == 0) redm[wv] = m;
  __syncthreads();
  m = fmaxf(fmaxf(redm[0], redm[1]), fmaxf(redm[2], redm[3]));
  float s = 0.f;
#pragma unroll
  for (int j = 0; j < 16; ++j) { x[j] = __expf(x[j] - m); s += x[j]; }
#pragma unroll
  for (int off = 1; off < 64; off <<= 1) s += __shfl_xor(s, off);
  if (ln == 0) reds[wv] = s;
  __syncthreads();
  s = (reds[0] + reds[1]) + (reds[2] + reds[3]);
  const float k = PSCALE / s;
#pragma unroll
  for (int j = 0; j < 8; ++j) { v0[j] = (f16)(x[j] * k); v1[j] = (f16)(x[8 + j] * k); }
  *(f16x8*)p = v0;
  *(f16x8*)(p + 8) = v1;
}

__global__ __launch_bounds__(256)
void k_tr_out(const f16* __restrict__ src, float* __restrict__ dst, float scale) {
  __shared__ float tile[64][65];
  const int m0 = blockIdx.x * 64, q0 = blockIdx.y * 64;
  const int tid = threadIdx.x;
  const int r = tid >> 2, c4 = (tid & 3) * 16;
  const f16* sp = src + (size_t)(q0 + r) * L + m0 + c4;
  f16x8 a = *(const f16x8*)sp;
  f16x8 b = *(const f16x8*)(sp + 8);
#pragma unroll
  for (int j = 0; j < 8; ++j) {
    tile[c4 + j][r] = (float)a[j] * scale;
    tile[c4 + 8 + j][r] = (float)b[j] * scale;
  }
  __syncthreads();
  float* dp = dst + (size_t)(m0 + r) * L + q0 + c4;
#pragma unroll
  for (int g = 0; g < 4; ++g) {
    float4 w;
    w.x = tile[r][c4 + 4 * g + 0];
    w.y = tile[r][c4 + 4 * g + 1];
    w.z = tile[r][c4 + 4 * g + 2];
    w.w = tile[r][c4 + 4 * g + 3];
    *(float4*)(dp + 4 * g) = w;
  }
}

extern "C" void kernel_launch(void* const* d_in, const int* in_sizes, int n_in,
                              void* d_out, int out_size, void* d_ws, size_t ws_size,
                              hipStream_t stream) {
  const float* m_k = (const float*)d_in[0];
  const float* m_v = (const float*)d_in[1];
  const float* q_k = (const float*)d_in[2];
  char* ws = (char*)d_ws;
  float* memOut = (float*)d_out;                  // [B][Dv][L]
  float* pOut = memOut + (size_t)NBATCH * DV * L; // [B][L][L] f32
  const size_t LL = (size_t)L * L;

  const bool fused = ws_size >= ((size_t)160 << 20);
  if (fused) {
    f16* pp = (f16*)ws;                                   // 128 MiB e'
    float* partial = (float*)(ws + ((size_t)128 << 20));  // 2 MiB
    f16* qkT = (f16*)(ws + ((size_t)131 << 20));          // 4 MiB
    f16* mkT = (f16*)(ws + ((size_t)135 << 20));          // 4 MiB
    f16* mvh = (f16*)(ws + ((size_t)139 << 20));          // 16 MiB
    k_tr2<<<dim3(L / 32, DK / 32, 8), dim3(32, 8), 0, stream>>>(q_k, m_k, qkT, mkT);
    k_cvt_f16<<<2048, 256, 0, stream>>>((const float4*)m_v, (f16x4*)mvh,
                                        NBATCH * DV * L / 4);
    // e'[q][m] = exp(s) f16 + per-block row expsum partials
    k_qk<<<dim3(L / 128, L / 128, NBATCH), 256, 0, stream>>>(
        qkT, mkT, pp, partial, 0.08838834764831845f);
    // barrier-free PV: mem + fused p writeback, rowinv from partials
    k_pv<<<1024, 256, 0, stream>>>(mvh, pp, partial, memOut, pOut);
  } else {
    // proven round-1 path
    f16* bounce = (f16*)ws;
    f16* qkT = (f16*)(ws + ((size_t)32 << 20));
    f16* mkT = (f16*)(ws + ((size_t)36 << 20));
    f16* mvh = (f16*)(ws + ((size_t)40 << 20));
    f16* pp = (f16*)(pOut + NBATCH * LL / 2);
    k_tr2<<<dim3(L / 32, DK / 32, 8), dim3(32, 8), 0, stream>>>(q_k, m_k, qkT, mkT);
    k_cvt_f16<<<2048, 256, 0, stream>>>((const float4*)m_v, (f16x4*)mvh,
                                        NBATCH * DV * L / 4);
    k_gemm_bt<true><<<dim3(L / 128, L / 128, NBATCH), 256, 0, stream>>>(
        qkT, mkT, (void*)pp, L, L, DK, 0.08838834764831845f);
    k_softmax<<<NBATCH * L, 256, 0, stream>>>(pp);
    hipMemcpyAsync(bounce, pp + 3 * LL, LL * sizeof(f16),
                   hipMemcpyDeviceToDevice, stream);
    k_gemm_bt<false><<<dim3(L / 128, DV / 128, NBATCH), 256, 0, stream>>>(
        mvh, pp, (void*)memOut, DV, L, L, 1.f / PSCALE);
    for (int b = 0; b < NBATCH; ++b) {
      const f16* src = (b == 3) ? bounce : (pp + (size_t)b * LL);
      k_tr_out<<<dim3(L / 64, L / 64), 256, 0, stream>>>(
          src, pOut + (size_t)b * LL, 1.f / PSCALE);
    }
  }
  (void)in_sizes; (void)n_in; (void)out_size; (void)ws_size;
}

// Round 11
// 171.635 us; speedup vs baseline: 2.4937x; 2.4937x over previous
//
#include <hip/hip_runtime.h>
#include <hip/hip_fp16.h>
#include <math.h>

typedef _Float16 f16;
typedef __attribute__((ext_vector_type(4))) _Float16 f16x4;
typedef __attribute__((ext_vector_type(8))) _Float16 f16x8;
typedef __attribute__((ext_vector_type(4))) float f32x4;

static constexpr int NBATCH = 4, DK = 128, DV = 512, L = 4096;
static constexpr float PSCALE = 256.f; // fallback path only

__device__ __forceinline__ void async16(const void* g, void* l) {
  __builtin_amdgcn_global_load_lds((const __attribute__((address_space(1))) void*)g,
                                   (__attribute__((address_space(3))) void*)l, 16, 0, 0);
}

// merged prep: z<4: transpose q_k batch z; z<8: transpose m_k batch z-4;
// z<12: convert m_v batch z-8 to f16. (proven R6)
__global__ void k_prep(const float* __restrict__ qk, const float* __restrict__ mk,
                       const float* __restrict__ mv, f16* __restrict__ qkT,
                       f16* __restrict__ mkT, f16* __restrict__ mvh) {
  const int z = blockIdx.z;
  const int tx = threadIdx.x, ty = threadIdx.y, tid = ty * 32 + tx;
  if (z < 8) {
    __shared__ float tile[32][33];
    const size_t bs = (size_t)DK * L;
    const float* inb = (z < 4 ? qk : mk) + (size_t)(z & 3) * bs;
    f16* outb = (z < 4 ? qkT : mkT) + (size_t)(z & 3) * bs;
    const int c0 = blockIdx.x * 32, r0 = blockIdx.y * 32;
#pragma unroll
    for (int i = 0; i < 32; i += 8)
      tile[ty + i][tx] = inb[(size_t)(r0 + ty + i) * L + (c0 + tx)];
    __syncthreads();
#pragma unroll
    for (int i = 0; i < 32; i += 8)
      outb[(size_t)(c0 + ty + i) * DK + (r0 + tx)] = (f16)tile[tx][ty + i];
  } else {
    const int zb = z - 8;
    const int bid = blockIdx.x + 128 * blockIdx.y; // 0..511
    const size_t base = (size_t)zb * (DV * L / 4) + (size_t)bid * 1024;
    const float4* in4 = (const float4*)mv;
    f16x4* out4 = (f16x4*)mvh;
#pragma unroll
    for (int k = 0; k < 4; ++k) {
      float4 v = in4[base + tid + k * 256];
      f16x4 o;
      o.x = (f16)v.x; o.y = (f16)v.y; o.z = (f16)v.z; o.w = (f16)v.w;
      out4[base + tid + k * 256] = o;
    }
  }
}

// C[z][row][col] = f(sum_k A[z][row][k] * B[z][col][k])
// A:[M][K] f16 row-major, B:[N][K] f16 row-major (both K-contiguous).
// 128x128 tile, BK=64, 4 waves (2x2), global_load_lds + XOR-source-swizzle.
// R5-proven single-buffer 2-barrier loop (structural plateau per R7-R10).
// MODE 0 (QK): e' = exp(s*oscale) f16 out (NORMAL stores - re-read by PV)
//              + per-block row expsum partials (no-max softmax).
// MODE 1 (PV): rowinv computed in prologue from partials (bit-identical);
//              f32 mem out (nt) scaled by rowinv[col]; by-fastest XCD chunk
//              (4 blocks sharing an e' B-panel co-resident on one XCD);
//              fused p-writeback (nt): block by owns m-quarter [1024*by,+1024).
template<int MODE>
__global__ __launch_bounds__(256, 2)
void k_gemm(const f16* __restrict__ A, const f16* __restrict__ B,
            void* __restrict__ C, float* __restrict__ aux,
            const float* __restrict__ aux2, float* __restrict__ P,
            int M, int N, int K, float oscale) {
  constexpr int BK = 64;
  __shared__ __align__(16) f16 As[128 * BK];
  __shared__ __align__(16) f16 Bs[128 * BK];
  __shared__ float sums[128];
  const int z = blockIdx.z;
  int bx = blockIdx.x, by = blockIdx.y;
  {
    const int n = gridDim.x * gridDim.y;
    const int id = bx + gridDim.x * by;
    const int id2 = (id & 7) * (n >> 3) + (id >> 3); // XCD chunk (n%8==0)
    if (MODE == 0) { bx = id2 % gridDim.x; by = id2 / gridDim.x; }
    else           { by = id2 % gridDim.y; bx = id2 / gridDim.y; }
  }
  const f16* Ab = A + (size_t)z * M * K;
  const f16* Bbp = B + (size_t)z * N * K;
  const int row0 = by * 128, col0 = bx * 128;
  const int tid = threadIdx.x, lane = tid & 63, wv = tid >> 6;
  const int wr = wv >> 1, wc = wv & 1;
  f32x4 acc[4][4] = {};
  const int srow = wv * 32 + (lane >> 3);
  const int sc = (lane & 7) ^ (lane >> 3); // source chunk pre-swizzle
  const f16* aSrc = Ab + (size_t)(row0 + srow) * K + sc * 8;
  const f16* bSrc = Bbp + (size_t)(col0 + srow) * K + sc * 8;
  f16* aDst = &As[(wv * 32) * BK];
  f16* bDst = &Bs[(wv * 32) * BK];
  float rv0 = 0.f, rv1 = 0.f;
  if (MODE == 1) {
    // rowinv for this block's 128 cols from partials (bit-identical sum order)
    if (tid < 128) {
      const float* pp_ = aux2 + (size_t)z * 32 * L + col0 + tid;
      float s = 0.f;
#pragma unroll
      for (int b = 0; b < 32; ++b) s += pp_[(size_t)b * L];
      sums[tid] = 1.f / s;
    }
    __syncthreads();
    rv0 = sums[lane];
    rv1 = sums[64 + lane];
  }

  for (int k0 = 0; k0 < K; k0 += BK) {
    __syncthreads();
#pragma unroll
    for (int j = 0; j < 4; ++j) {
      async16(aSrc + (size_t)(j * 8) * K + k0, aDst + (j * 8) * BK);
      async16(bSrc + (size_t)(j * 8) * K + k0, bDst + (j * 8) * BK);
    }
    __syncthreads();
#pragma unroll
    for (int kk = 0; kk < BK / 32; ++kk) {
      const int cx = ((kk * 4 + (lane >> 4)) ^ (lane & 7)) * 8;
      f16x8 av[4], bv[4];
#pragma unroll
      for (int i = 0; i < 4; ++i) {
        av[i] = *(const f16x8*)&As[(wr * 64 + i * 16 + (lane & 15)) * BK + cx];
        bv[i] = *(const f16x8*)&Bs[(wc * 64 + i * 16 + (lane & 15)) * BK + cx];
      }
#pragma unroll
      for (int i = 0; i < 4; ++i)
#pragma unroll
        for (int j = 0; j < 4; ++j)
          acc[i][j] = __builtin_amdgcn_mfma_f32_16x16x32_f16(av[i], bv[j], acc[i][j], 0, 0, 0);
    }
    if (MODE == 1) {
      // fused p-writeback from the LDS B-tile (buffer freed at next barrier)
      if ((k0 >> 10) == by) {
#pragma unroll
        for (int h = 0; h < 2; ++h) {
          const int cc = wv * 2 + h; // this wave's 8-m chunk (0..7)
#pragma unroll
          for (int qh = 0; qh < 2; ++qh) {
            const int q = qh * 64 + lane;
            const f16x8 ev =
                *(const f16x8*)&Bs[q * BK + ((cc ^ (q & 7)) * 8)];
            const float rv = qh ? rv1 : rv0;
            float* pr = P + (size_t)z * L * L + (size_t)(k0 + cc * 8) * L + col0 + q;
#pragma unroll
            for (int j = 0; j < 8; ++j)
              __builtin_nontemporal_store((float)ev[j] * rv, pr + (size_t)j * L);
          }
        }
      }
    }
  }
  // C/D layout: col = lane&15, row = (lane>>4)*4 + t
  const size_t cb = (size_t)z * M * N;
  const int er = (lane >> 4) * 4, ec = lane & 15;
  if (MODE == 0) {
    // e' = exp(acc*oscale) f16 out + per-row expsum partials (no-max softmax)
    float rp[16];
#pragma unroll
    for (int u = 0; u < 16; ++u) rp[u] = 0.f;
#pragma unroll
    for (int i = 0; i < 4; ++i) {
      const int r = row0 + wr * 64 + i * 16 + er;
#pragma unroll
      for (int j = 0; j < 4; ++j) {
        const int c = col0 + wc * 64 + j * 16 + ec;
#pragma unroll
        for (int t = 0; t < 4; ++t) {
          const float e = __expf(acc[i][j][t] * oscale);
          ((f16*)C)[cb + (size_t)(r + t) * N + c] = (f16)e;
          rp[i * 4 + t] += e;
        }
      }
    }
#pragma unroll
    for (int u = 0; u < 16; ++u) {
      rp[u] += __shfl_xor(rp[u], 1);
      rp[u] += __shfl_xor(rp[u], 2);
      rp[u] += __shfl_xor(rp[u], 4);
      rp[u] += __shfl_xor(rp[u], 8);
    }
    // combine the two col-waves (wc): exactly 2 addends -> deterministic
    if (wc == 1 && (lane & 15) == 0) {
#pragma unroll
      for (int i = 0; i < 4; ++i)
#pragma unroll
        for (int t = 0; t < 4; ++t)
          sums[wr * 64 + i * 16 + (lane >> 4) * 4 + t] = rp[i * 4 + t];
    }
    __syncthreads();
    if (wc == 0 && (lane & 15) == 0) {
#pragma unroll
      for (int i = 0; i < 4; ++i)
#pragma unroll
        for (int t = 0; t < 4; ++t) {
          const int r = wr * 64 + i * 16 + (lane >> 4) * 4 + t;
          aux[((size_t)z * gridDim.x + bx) * L + row0 + r] = rp[i * 4 + t] + sums[r];
        }
    }
  } else {
    // PV: scale output columns by rowinv (from LDS), nt stores (never re-read)
    float rv[4];
#pragma unroll
    for (int j = 0; j < 4; ++j) rv[j] = sums[wc * 64 + j * 16 + ec];
#pragma unroll
    for (int i = 0; i < 4; ++i) {
      const int r = row0 + wr * 64 + i * 16 + er;
#pragma unroll
      for (int j = 0; j < 4; ++j) {
        const int c = col0 + wc * 64 + j * 16 + ec;
#pragma unroll
        for (int t = 0; t < 4; ++t)
          __builtin_nontemporal_store(acc[i][j][t] * rv[j],
                                      &((float*)C)[cb + (size_t)(r + t) * N + c]);
      }
    }
  }
}

// ---------------- fallback-path kernels (proven round-1) ----------------
template<bool OUT_F16>
__global__ __launch_bounds__(256, 2)
void k_gemm_bt(const f16* __restrict__ A, const f16* __restrict__ B,
               void* __restrict__ C, int M, int N, int K, float oscale) {
  constexpr int BK = 64;
  __shared__ __align__(16) f16 As[128 * BK];
  __shared__ __align__(16) f16 Bs[128 * BK];
  const int z = blockIdx.z;
  const f16* Ab = A + (size_t)z * M * K;
  const f16* Bbp = B + (size_t)z * N * K;
  const int row0 = blockIdx.y * 128, col0 = blockIdx.x * 128;
  const int tid = threadIdx.x, lane = tid & 63, wv = tid >> 6;
  const int wr = wv >> 1, wc = wv & 1;
  f32x4 acc[4][4] = {};
  const int srow = wv * 32 + (lane >> 3);
  const int sc = (lane & 7) ^ (lane >> 3);
  const f16* aSrc = Ab + (size_t)(row0 + srow) * K + sc * 8;
  const f16* bSrc = Bbp + (size_t)(col0 + srow) * K + sc * 8;
  f16* aDst = &As[(wv * 32) * BK];
  f16* bDst = &Bs[(wv * 32) * BK];
  for (int k0 = 0; k0 < K; k0 += BK) {
    __syncthreads();
#pragma unroll
    for (int j = 0; j < 4; ++j) {
      async16(aSrc + (size_t)(j * 8) * K + k0, aDst + (j * 8) * BK);
      async16(bSrc + (size_t)(j * 8) * K + k0, bDst + (j * 8) * BK);
    }
    __syncthreads();
#pragma unroll
    for (int kk = 0; kk < BK / 32; ++kk) {
      const int cx = ((kk * 4 + (lane >> 4)) ^ (lane & 7)) * 8;
      f16x8 av[4], bv[4];
#pragma unroll
      for (int i = 0; i < 4; ++i) {
        av[i] = *(const f16x8*)&As[(wr * 64 + i * 16 + (lane & 15)) * BK + cx];
        bv[i] = *(const f16x8*)&Bs[(wc * 64 + i * 16 + (lane & 15)) * BK + cx];
      }
#pragma unroll
      for (int i = 0; i < 4; ++i)
#pragma unroll
        for (int j = 0; j < 4; ++j)
          acc[i][j] = __builtin_amdgcn_mfma_f32_16x16x32_f16(av[i], bv[j], acc[i][j], 0, 0, 0);
    }
  }
  const size_t cb = (size_t)z * M * N;
  const int er = (lane >> 4) * 4, ec = lane & 15;
#pragma unroll
  for (int i = 0; i < 4; ++i) {
    const int r = row0 + wr * 64 + i * 16 + er;
#pragma unroll
    for (int j = 0; j < 4; ++j) {
      const int c = col0 + wc * 64 + j * 16 + ec;
#pragma unroll
      for (int t = 0; t < 4; ++t) {
        const float v = acc[i][j][t] * oscale;
        if (OUT_F16) ((f16*)C)[cb + (size_t)(r + t) * N + c] = (f16)v;
        else        ((float*)C)[cb + (size_t)(r + t) * N + c] = v;
      }
    }
  }
}

__global__ __launch_bounds__(256)
void k_softmax(f16* __restrict__ S) {
  const size_t rowbase = (size_t)blockIdx.x * L;
  const int tid = threadIdx.x, ln = tid & 63, wv = tid >> 6;
  f16* p = S + rowbase + tid * 16;
  f16x8 v0 = *(const f16x8*)p;
  f16x8 v1 = *(const f16x8*)(p + 8);
  float x[16];
#pragma unroll
  for (int j = 0; j < 8; ++j) { x[j] = (float)v0[j]; x[8 + j] = (float)v1[j]; }
  float m = -3.0e38f;
#pragma unroll
  for (int j = 0; j < 16; ++j) m = fmaxf(m, x[j]);
#pragma unroll
  for (int off = 1; off < 64; off <<= 1) m = fmaxf(m, __shfl_xor(m, off));
  __shared__ float redm[4], reds[4];
  if (ln == 0) redm[wv] = m;
  __syncthreads();
  m = fmaxf(fmaxf(redm[0], redm[1]), fmaxf(redm[2], redm[3]));
  float s = 0.f;
#pragma unroll
  for (int j = 0; j < 16; ++j) { x[j] = __expf(x[j] - m); s += x[j]; }
#pragma unroll
  for (int off = 1; off < 64; off <<= 1) s += __shfl_xor(s, off);
  if (ln == 0) reds[wv] = s;
  __syncthreads();
  s = (reds[0] + reds[1]) + (reds[2] + reds[3]);
  const float k = PSCALE / s;
#pragma unroll
  for (int j = 0; j < 8; ++j) { v0[j] = (f16)(x[j] * k); v1[j] = (f16)(x[8 + j] * k); }
  *(f16x8*)p = v0;
  *(f16x8*)(p + 8) = v1;
}

__global__ __launch_bounds__(256)
void k_tr_out(const f16* __restrict__ src, float* __restrict__ dst, float scale) {
  __shared__ float tile[64][65];
  const int m0 = blockIdx.x * 64, q0 = blockIdx.y * 64;
  const int tid = threadIdx.x;
  const int r = tid >> 2, c4 = (tid & 3) * 16;
  const f16* sp = src + (size_t)(q0 + r) * L + m0 + c4;
  f16x8 a = *(const f16x8*)sp;
  f16x8 b = *(const f16x8*)(sp + 8);
#pragma unroll
  for (int j = 0; j < 8; ++j) {
    tile[c4 + j][r] = (float)a[j] * scale;
    tile[c4 + 8 + j][r] = (float)b[j] * scale;
  }
  __syncthreads();
  float* dp = dst + (size_t)(m0 + r) * L + q0 + c4;
#pragma unroll
  for (int g = 0; g < 4; ++g) {
    float4 w;
    w.x = tile[r][c4 + 4 * g + 0];
    w.y = tile[r][c4 + 4 * g + 1];
    w.z = tile[r][c4 + 4 * g + 2];
    w.w = tile[r][c4 + 4 * g + 3];
    *(float4*)(dp + 4 * g) = w;
  }
}

extern "C" void kernel_launch(void* const* d_in, const int* in_sizes, int n_in,
                              void* d_out, int out_size, void* d_ws, size_t ws_size,
                              hipStream_t stream) {
  const float* m_k = (const float*)d_in[0];
  const float* m_v = (const float*)d_in[1];
  const float* q_k = (const float*)d_in[2];
  char* ws = (char*)d_ws;
  float* memOut = (float*)d_out;                  // [B][Dv][L]
  float* pOut = memOut + (size_t)NBATCH * DV * L; // [B][L][L] f32
  const size_t LL = (size_t)L * L;

  const bool fused = ws_size >= ((size_t)160 << 20);
  if (fused) {
    f16* pp = (f16*)ws;                                   // 128 MiB e'
    float* partial = (float*)(ws + ((size_t)128 << 20));  // 2 MiB
    f16* qkT = (f16*)(ws + ((size_t)131 << 20));          // 4 MiB
    f16* mkT = (f16*)(ws + ((size_t)135 << 20));          // 4 MiB
    f16* mvh = (f16*)(ws + ((size_t)139 << 20));          // 16 MiB
    // merged prep: both transposes + mvh convert in one launch
    k_prep<<<dim3(L / 32, DK / 32, 12), dim3(32, 8), 0, stream>>>(
        q_k, m_k, m_v, qkT, mkT, mvh);
    // e'[q][m] = exp(s) f16 + per-block row expsum partials
    k_gemm<0><<<dim3(L / 128, L / 128, NBATCH), 256, 0, stream>>>(
        qkT, mkT, (void*)pp, partial, nullptr, nullptr, L, L, DK,
        0.08838834764831845f);
    // mem[v][q] = rowinv[q]*sum_m mv[v][m]*e'[q][m]; fused p[m][q] writeback;
    // rowinv computed in PV prologue from partials (bit-identical order)
    k_gemm<1><<<dim3(L / 128, DV / 128, NBATCH), 256, 0, stream>>>(
        mvh, pp, (void*)memOut, nullptr, partial, pOut, DV, L, L, 1.f);
  } else {
    // proven round-1 path
    f16* bounce = (f16*)ws;
    f16* qkT = (f16*)(ws + ((size_t)32 << 20));
    f16* mkT = (f16*)(ws + ((size_t)36 << 20));
    f16* mvh = (f16*)(ws + ((size_t)40 << 20));
    f16* pp = (f16*)(pOut + NBATCH * LL / 2);
    k_prep<<<dim3(L / 32, DK / 32, 12), dim3(32, 8), 0, stream>>>(
        q_k, m_k, m_v, qkT, mkT, mvh);
    k_gemm_bt<true><<<dim3(L / 128, L / 128, NBATCH), 256, 0, stream>>>(
        qkT, mkT, (void*)pp, L, L, DK, 0.08838834764831845f);
    k_softmax<<<NBATCH * L, 256, 0, stream>>>(pp);
    hipMemcpyAsync(bounce, pp + 3 * LL, LL * sizeof(f16),
                   hipMemcpyDeviceToDevice, stream);
    k_gemm_bt<false><<<dim3(L / 128, DV / 128, NBATCH), 256, 0, stream>>>(
        mvh, pp, (void*)memOut, DV, L, L, 1.f / PSCALE);
    for (int b = 0; b < NBATCH; ++b) {
      const f16* src = (b == 3) ? bounce : (pp + (size_t)b * LL);
      k_tr_out<<<dim3(L / 64, L / 64), 256, 0, stream>>>(
          src, pOut + (size_t)b * LL, 1.f / PSCALE);
    }
  }
  (void)in_sizes; (void)n_in; (void)out_size; (void)ws_size;
}

// Round 12
// 167.767 us; speedup vs baseline: 2.5512x; 1.0231x over previous
//
#include <hip/hip_runtime.h>
#include <hip/hip_fp16.h>
#include <math.h>

typedef _Float16 f16;
typedef __attribute__((ext_vector_type(4))) _Float16 f16x4;
typedef __attribute__((ext_vector_type(8))) _Float16 f16x8;
typedef __attribute__((ext_vector_type(4))) float f32x4;

static constexpr int NBATCH = 4, DK = 128, DV = 512, L = 4096;
static constexpr float PSCALE = 256.f; // fallback path only

__device__ __forceinline__ void async16(const void* g, void* l) {
  __builtin_amdgcn_global_load_lds((const __attribute__((address_space(1))) void*)g,
                                   (__attribute__((address_space(3))) void*)l, 16, 0, 0);
}

// merged prep: z<4: transpose q_k batch z; z<8: transpose m_k batch z-4;
// z<12: convert m_v batch z-8 to f16. (proven R6/R11)
__global__ void k_prep(const float* __restrict__ qk, const float* __restrict__ mk,
                       const float* __restrict__ mv, f16* __restrict__ qkT,
                       f16* __restrict__ mkT, f16* __restrict__ mvh) {
  const int z = blockIdx.z;
  const int tx = threadIdx.x, ty = threadIdx.y, tid = ty * 32 + tx;
  if (z < 8) {
    __shared__ float tile[32][33];
    const size_t bs = (size_t)DK * L;
    const float* inb = (z < 4 ? qk : mk) + (size_t)(z & 3) * bs;
    f16* outb = (z < 4 ? qkT : mkT) + (size_t)(z & 3) * bs;
    const int c0 = blockIdx.x * 32, r0 = blockIdx.y * 32;
#pragma unroll
    for (int i = 0; i < 32; i += 8)
      tile[ty + i][tx] = inb[(size_t)(r0 + ty + i) * L + (c0 + tx)];
    __syncthreads();
#pragma unroll
    for (int i = 0; i < 32; i += 8)
      outb[(size_t)(c0 + ty + i) * DK + (r0 + tx)] = (f16)tile[tx][ty + i];
  } else {
    const int zb = z - 8;
    const int bid = blockIdx.x + 128 * blockIdx.y; // 0..511
    const size_t base = (size_t)zb * (DV * L / 4) + (size_t)bid * 1024;
    const float4* in4 = (const float4*)mv;
    f16x4* out4 = (f16x4*)mvh;
#pragma unroll
    for (int k = 0; k < 4; ++k) {
      float4 v = in4[base + tid + k * 256];
      f16x4 o;
      o.x = (f16)v.x; o.y = (f16)v.y; o.z = (f16)v.z; o.w = (f16)v.w;
      out4[base + tid + k * 256] = o;
    }
  }
}

// QK (R11-proven): e'[z][q][m] = exp(oscale*sum_k qkT[q][k]*mkT[m][k]) f16
// (normal stores - re-read by PV) + per-block row expsum partials.
__global__ __launch_bounds__(256, 2)
void k_qk(const f16* __restrict__ A, const f16* __restrict__ B,
          f16* __restrict__ C, float* __restrict__ aux, float oscale) {
  constexpr int BK = 64;
  const int M = L, N = L, K = DK;
  __shared__ __align__(16) f16 As[128 * BK];
  __shared__ __align__(16) f16 Bs[128 * BK];
  __shared__ float sums[128];
  const int z = blockIdx.z;
  int bx = blockIdx.x, by = blockIdx.y;
  {
    const int n = gridDim.x * gridDim.y;
    const int id = bx + gridDim.x * by;
    const int id2 = (id & 7) * (n >> 3) + (id >> 3); // XCD chunk (n%8==0)
    bx = id2 % gridDim.x;
    by = id2 / gridDim.x;
  }
  const f16* Ab = A + (size_t)z * M * K;
  const f16* Bbp = B + (size_t)z * N * K;
  const int row0 = by * 128, col0 = bx * 128;
  const int tid = threadIdx.x, lane = tid & 63, wv = tid >> 6;
  const int wr = wv >> 1, wc = wv & 1;
  f32x4 acc[4][4] = {};
  const int srow = wv * 32 + (lane >> 3);
  const int sc = (lane & 7) ^ (lane >> 3); // source chunk pre-swizzle
  const f16* aSrc = Ab + (size_t)(row0 + srow) * K + sc * 8;
  const f16* bSrc = Bbp + (size_t)(col0 + srow) * K + sc * 8;
  f16* aDst = &As[(wv * 32) * BK];
  f16* bDst = &Bs[(wv * 32) * BK];

  for (int k0 = 0; k0 < K; k0 += BK) {
    __syncthreads();
#pragma unroll
    for (int j = 0; j < 4; ++j) {
      async16(aSrc + (size_t)(j * 8) * K + k0, aDst + (j * 8) * BK);
      async16(bSrc + (size_t)(j * 8) * K + k0, bDst + (j * 8) * BK);
    }
    __syncthreads();
#pragma unroll
    for (int kk = 0; kk < BK / 32; ++kk) {
      const int cx = ((kk * 4 + (lane >> 4)) ^ (lane & 7)) * 8;
      f16x8 av[4], bv[4];
#pragma unroll
      for (int i = 0; i < 4; ++i) {
        av[i] = *(const f16x8*)&As[(wr * 64 + i * 16 + (lane & 15)) * BK + cx];
        bv[i] = *(const f16x8*)&Bs[(wc * 64 + i * 16 + (lane & 15)) * BK + cx];
      }
#pragma unroll
      for (int i = 0; i < 4; ++i)
#pragma unroll
        for (int j = 0; j < 4; ++j)
          acc[i][j] = __builtin_amdgcn_mfma_f32_16x16x32_f16(av[i], bv[j], acc[i][j], 0, 0, 0);
    }
  }
  const size_t cb = (size_t)z * M * N;
  const int er = (lane >> 4) * 4, ec = lane & 15;
  float rp[16];
#pragma unroll
  for (int u = 0; u < 16; ++u) rp[u] = 0.f;
#pragma unroll
  for (int i = 0; i < 4; ++i) {
    const int r = row0 + wr * 64 + i * 16 + er;
#pragma unroll
    for (int j = 0; j < 4; ++j) {
      const int c = col0 + wc * 64 + j * 16 + ec;
#pragma unroll
      for (int t = 0; t < 4; ++t) {
        const float e = __expf(acc[i][j][t] * oscale);
        C[cb + (size_t)(r + t) * N + c] = (f16)e;
        rp[i * 4 + t] += e;
      }
    }
  }
#pragma unroll
  for (int u = 0; u < 16; ++u) {
    rp[u] += __shfl_xor(rp[u], 1);
    rp[u] += __shfl_xor(rp[u], 2);
    rp[u] += __shfl_xor(rp[u], 4);
    rp[u] += __shfl_xor(rp[u], 8);
  }
  if (wc == 1 && (lane & 15) == 0) {
#pragma unroll
    for (int i = 0; i < 4; ++i)
#pragma unroll
      for (int t = 0; t < 4; ++t)
        sums[wr * 64 + i * 16 + (lane >> 4) * 4 + t] = rp[i * 4 + t];
  }
  __syncthreads();
  if (wc == 0 && (lane & 15) == 0) {
#pragma unroll
    for (int i = 0; i < 4; ++i)
#pragma unroll
      for (int t = 0; t < 4; ++t) {
        const int r = wr * 64 + i * 16 + (lane >> 4) * 4 + t;
        aux[((size_t)z * gridDim.x + bx) * L + row0 + r] = rp[i * 4 + t] + sums[r];
      }
  }
}

// PV with double-buffer + raw barriers + STORE-AWARE counted vmcnt.
// mem[z][v][q] = rowinv[q]*sum_m mvh[v][m]*e'[q][m] (nt out) + fused
// p[z][m][q] writeback (nt; block by owns m-quarter [1024*by,+1024)).
// vmcnt(8): tile-t loads drained, t+1 loads in flight.
// vmcnt(40) after a writeback step: additionally leaves the 32 p-stores
// in flight across the whole next stage+MFMA phase (in-order vmcnt
// retirement guarantees the oldest 8 loads ARE drained).
__global__ __launch_bounds__(256, 2)
void k_pv(const f16* __restrict__ A, const f16* __restrict__ B,
          float* __restrict__ C, const float* __restrict__ partial,
          float* __restrict__ P) {
  constexpr int BK = 64;
  const int M = DV, N = L, K = L;
  __shared__ __align__(16) f16 As[2][128 * BK];
  __shared__ __align__(16) f16 Bs[2][128 * BK];
  __shared__ float sums[128];
  const int z = blockIdx.z;
  int bx = blockIdx.x, by = blockIdx.y;
  {
    const int n = gridDim.x * gridDim.y; // 128
    const int id = bx + gridDim.x * by;
    const int id2 = (id & 7) * (n >> 3) + (id >> 3); // XCD chunk
    by = id2 % gridDim.y;  // by-fastest: 4 v-blocks of one q-panel co-XCD
    bx = id2 / gridDim.y;
  }
  const f16* Ab = A + (size_t)z * M * K;
  const f16* Bbp = B + (size_t)z * N * K;
  const int row0 = by * 128, col0 = bx * 128;
  const int tid = threadIdx.x, lane = tid & 63, wv = tid >> 6;
  const int wr = wv >> 1, wc = wv & 1;
  f32x4 acc[4][4] = {};
  const int srow = wv * 32 + (lane >> 3);
  const int sc = (lane & 7) ^ (lane >> 3);
  const f16* aSrc = Ab + (size_t)(row0 + srow) * K + sc * 8;
  const f16* bSrc = Bbp + (size_t)(col0 + srow) * K + sc * 8;
  const int dOff = (wv * 32) * BK;

  // rowinv prologue from partials (bit-identical bx-ascending sum order)
  if (tid < 128) {
    const float* pp_ = partial + (size_t)z * 32 * L + col0 + tid;
    float s = 0.f;
#pragma unroll
    for (int b = 0; b < 32; ++b) s += pp_[(size_t)b * L];
    sums[tid] = 1.f / s;
  }
  __syncthreads();
  const float rv0 = sums[lane];
  const float rv1 = sums[64 + lane];

  const int nt = K / BK; // 64
  // prologue: stage tile 0 into buf 0 (8 loads/wave)
#pragma unroll
  for (int j = 0; j < 4; ++j) {
    async16(aSrc + (size_t)(j * 8) * K, &As[0][dOff + (j * 8) * BK]);
    async16(bSrc + (size_t)(j * 8) * K, &Bs[0][dOff + (j * 8) * BK]);
  }

  for (int t = 0; t < nt; ++t) {
    const int cur = t & 1;
    // WAR barrier (raw): all waves done reading buf[cur^1] at t-1
    __builtin_amdgcn_s_barrier();
    if (t + 1 < nt) {
      const int k0n = (t + 1) * BK;
#pragma unroll
      for (int j = 0; j < 4; ++j) {
        async16(aSrc + (size_t)(j * 8) * K + k0n, &As[cur ^ 1][dOff + (j * 8) * BK]);
        async16(bSrc + (size_t)(j * 8) * K + k0n, &Bs[cur ^ 1][dOff + (j * 8) * BK]);
      }
      if (t >= 1 && ((t - 1) >> 4) == by) {
        // 32 p-stores (prev step) + 8 new loads stay in flight; oldest 8
        // (tile-t loads) guaranteed retired by in-order vmcnt counting.
        asm volatile("s_waitcnt vmcnt(40)" ::: "memory");
      } else {
        asm volatile("s_waitcnt vmcnt(8)" ::: "memory");
      }
    } else {
      asm volatile("s_waitcnt vmcnt(0)" ::: "memory");
    }
    __builtin_amdgcn_s_barrier(); // all waves have tile t resident
#pragma unroll
    for (int kk = 0; kk < BK / 32; ++kk) {
      const int cx = ((kk * 4 + (lane >> 4)) ^ (lane & 7)) * 8;
      f16x8 av[4], bv[4];
#pragma unroll
      for (int i = 0; i < 4; ++i) {
        av[i] = *(const f16x8*)&As[cur][(wr * 64 + i * 16 + (lane & 15)) * BK + cx];
        bv[i] = *(const f16x8*)&Bs[cur][(wc * 64 + i * 16 + (lane & 15)) * BK + cx];
      }
#pragma unroll
      for (int i = 0; i < 4; ++i)
#pragma unroll
        for (int j = 0; j < 4; ++j)
          acc[i][j] = __builtin_amdgcn_mfma_f32_16x16x32_f16(av[i], bv[j], acc[i][j], 0, 0, 0);
    }
    // fused p-writeback from LDS B-tile (nt stores; drained lazily above)
    if ((t >> 4) == by) {
      const int k0 = t * BK;
#pragma unroll
      for (int h = 0; h < 2; ++h) {
        const int cc = wv * 2 + h; // this wave's 8-m chunk (0..7)
#pragma unroll
        for (int qh = 0; qh < 2; ++qh) {
          const int q = qh * 64 + lane;
          const f16x8 ev = *(const f16x8*)&Bs[cur][q * BK + ((cc ^ (q & 7)) * 8)];
          const float rv = qh ? rv1 : rv0;
          float* pr = P + (size_t)z * L * L + (size_t)(k0 + cc * 8) * L + col0 + q;
#pragma unroll
          for (int j = 0; j < 8; ++j)
            __builtin_nontemporal_store((float)ev[j] * rv, pr + (size_t)j * L);
        }
      }
    }
  }
  // mem epilogue: col = lane&15, row = (lane>>4)*4 + t (nt, never re-read)
  const size_t cb = (size_t)z * M * N;
  const int er = (lane >> 4) * 4, ec = lane & 15;
  float rvj[4];
#pragma unroll
  for (int j = 0; j < 4; ++j) rvj[j] = sums[wc * 64 + j * 16 + ec];
#pragma unroll
  for (int i = 0; i < 4; ++i) {
    const int r = row0 + wr * 64 + i * 16 + er;
#pragma unroll
    for (int j = 0; j < 4; ++j) {
      const int c = col0 + wc * 64 + j * 16 + ec;
#pragma unroll
      for (int t = 0; t < 4; ++t)
        __builtin_nontemporal_store(acc[i][j][t] * rvj[j],
                                    &C[cb + (size_t)(r + t) * N + c]);
    }
  }
}

// ---------------- fallback-path kernels (proven round-1) ----------------
template<bool OUT_F16>
__global__ __launch_bounds__(256, 2)
void k_gemm_bt(const f16* __restrict__ A, const f16* __restrict__ B,
               void* __restrict__ C, int M, int N, int K, float oscale) {
  constexpr int BK = 64;
  __shared__ __align__(16) f16 As[128 * BK];
  __shared__ __align__(16) f16 Bs[128 * BK];
  const int z = blockIdx.z;
  const f16* Ab = A + (size_t)z * M * K;
  const f16* Bbp = B + (size_t)z * N * K;
  const int row0 = blockIdx.y * 128, col0 = blockIdx.x * 128;
  const int tid = threadIdx.x, lane = tid & 63, wv = tid >> 6;
  const int wr = wv >> 1, wc = wv & 1;
  f32x4 acc[4][4] = {};
  const int srow = wv * 32 + (lane >> 3);
  const int sc = (lane & 7) ^ (lane >> 3);
  const f16* aSrc = Ab + (size_t)(row0 + srow) * K + sc * 8;
  const f16* bSrc = Bbp + (size_t)(col0 + srow) * K + sc * 8;
  f16* aDst = &As[(wv * 32) * BK];
  f16* bDst = &Bs[(wv * 32) * BK];
  for (int k0 = 0; k0 < K; k0 += BK) {
    __syncthreads();
#pragma unroll
    for (int j = 0; j < 4; ++j) {
      async16(aSrc + (size_t)(j * 8) * K + k0, aDst + (j * 8) * BK);
      async16(bSrc + (size_t)(j * 8) * K + k0, bDst + (j * 8) * BK);
    }
    __syncthreads();
#pragma unroll
    for (int kk = 0; kk < BK / 32; ++kk) {
      const int cx = ((kk * 4 + (lane >> 4)) ^ (lane & 7)) * 8;
      f16x8 av[4], bv[4];
#pragma unroll
      for (int i = 0; i < 4; ++i) {
        av[i] = *(const f16x8*)&As[(wr * 64 + i * 16 + (lane & 15)) * BK + cx];
        bv[i] = *(const f16x8*)&Bs[(wc * 64 + i * 16 + (lane & 15)) * BK + cx];
      }
#pragma unroll
      for (int i = 0; i < 4; ++i)
#pragma unroll
        for (int j = 0; j < 4; ++j)
          acc[i][j] = __builtin_amdgcn_mfma_f32_16x16x32_f16(av[i], bv[j], acc[i][j], 0, 0, 0);
    }
  }
  const size_t cb = (size_t)z * M * N;
  const int er = (lane >> 4) * 4, ec = lane & 15;
#pragma unroll
  for (int i = 0; i < 4; ++i) {
    const int r = row0 + wr * 64 + i * 16 + er;
#pragma unroll
    for (int j = 0; j < 4; ++j) {
      const int c = col0 + wc * 64 + j * 16 + ec;
#pragma unroll
      for (int t = 0; t < 4; ++t) {
        const float v = acc[i][j][t] * oscale;
        if (OUT_F16) ((f16*)C)[cb + (size_t)(r + t) * N + c] = (f16)v;
        else        ((float*)C)[cb + (size_t)(r + t) * N + c] = v;
      }
    }
  }
}

__global__ __launch_bounds__(256)
void k_softmax(f16* __restrict__ S) {
  const size_t rowbase = (size_t)blockIdx.x * L;
  const int tid = threadIdx.x, ln = tid & 63, wv = tid >> 6;
  f16* p = S + rowbase + tid * 16;
  f16x8 v0 = *(const f16x8*)p;
  f16x8 v1 = *(const f16x8*)(p + 8);
  float x[16];
#pragma unroll
  for (int j = 0; j < 8; ++j) { x[j] = (float)v0[j]; x[8 + j] = (float)v1[j]; }
  float m = -3.0e38f;
#pragma unroll
  for (int j = 0; j < 16; ++j) m = fmaxf(m, x[j]);
#pragma unroll
  for (int off = 1; off < 64; off <<= 1) m = fmaxf(m, __shfl_xor(m, off));
  __shared__ float redm[4], reds[4];
  if (ln == 0) redm[wv] = m;
  __syncthreads();
  m = fmaxf(fmaxf(redm[0], redm[1]), fmaxf(redm[2], redm[3]));
  float s = 0.f;
#pragma unroll
  for (int j = 0; j < 16; ++j) { x[j] = __expf(x[j] - m); s += x[j]; }
#pragma unroll
  for (int off = 1; off < 64; off <<= 1) s += __shfl_xor(s, off);
  if (ln == 0) reds[wv] = s;
  __syncthreads();
  s = (reds[0] + reds[1]) + (reds[2] + reds[3]);
  const float k = PSCALE / s;
#pragma unroll
  for (int j = 0; j < 8; ++j) { v0[j] = (f16)(x[j] * k); v1[j] = (f16)(x[8 + j] * k); }
  *(f16x8*)p = v0;
  *(f16x8*)(p + 8) = v1;
}

__global__ __launch_bounds__(256)
void k_tr_out(const f16* __restrict__ src, float* __restrict__ dst, float scale) {
  __shared__ float tile[64][65];
  const int m0 = blockIdx.x * 64, q0 = blockIdx.y * 64;
  const int tid = threadIdx.x;
  const int r = tid >> 2, c4 = (tid & 3) * 16;
  const f16* sp = src + (size_t)(q0 + r) * L + m0 + c4;
  f16x8 a = *(const f16x8*)sp;
  f16x8 b = *(const f16x8*)(sp + 8);
#pragma unroll
  for (int j = 0; j < 8; ++j) {
    tile[c4 + j][r] = (float)a[j] * scale;
    tile[c4 + 8 + j][r] = (float)b[j] * scale;
  }
  __syncthreads();
  float* dp = dst + (size_t)(m0 + r) * L + q0 + c4;
#pragma unroll
  for (int g = 0; g < 4; ++g) {
    float4 w;
    w.x = tile[r][c4 + 4 * g + 0];
    w.y = tile[r][c4 + 4 * g + 1];
    w.z = tile[r][c4 + 4 * g + 2];
    w.w = tile[r][c4 + 4 * g + 3];
    *(float4*)(dp + 4 * g) = w;
  }
}

extern "C" void kernel_launch(void* const* d_in, const int* in_sizes, int n_in,
                              void* d_out, int out_size, void* d_ws, size_t ws_size,
                              hipStream_t stream) {
  const float* m_k = (const float*)d_in[0];
  const float* m_v = (const float*)d_in[1];
  const float* q_k = (const float*)d_in[2];
  char* ws = (char*)d_ws;
  float* memOut = (float*)d_out;                  // [B][Dv][L]
  float* pOut = memOut + (size_t)NBATCH * DV * L; // [B][L][L] f32
  const size_t LL = (size_t)L * L;

  const bool fused = ws_size >= ((size_t)160 << 20);
  if (fused) {
    f16* pp = (f16*)ws;                                   // 128 MiB e'
    float* partial = (float*)(ws + ((size_t)128 << 20));  // 2 MiB
    f16* qkT = (f16*)(ws + ((size_t)131 << 20));          // 4 MiB
    f16* mkT = (f16*)(ws + ((size_t)135 << 20));          // 4 MiB
    f16* mvh = (f16*)(ws + ((size_t)139 << 20));          // 16 MiB
    k_prep<<<dim3(L / 32, DK / 32, 12), dim3(32, 8), 0, stream>>>(
        q_k, m_k, m_v, qkT, mkT, mvh);
    k_qk<<<dim3(L / 128, L / 128, NBATCH), 256, 0, stream>>>(
        qkT, mkT, pp, partial, 0.08838834764831845f);
    k_pv<<<dim3(L / 128, DV / 128, NBATCH), 256, 0, stream>>>(
        mvh, pp, memOut, partial, pOut);
  } else {
    // proven round-1 path
    f16* bounce = (f16*)ws;
    f16* qkT = (f16*)(ws + ((size_t)32 << 20));
    f16* mkT = (f16*)(ws + ((size_t)36 << 20));
    f16* mvh = (f16*)(ws + ((size_t)40 << 20));
    f16* pp = (f16*)(pOut + NBATCH * LL / 2);
    k_prep<<<dim3(L / 32, DK / 32, 12), dim3(32, 8), 0, stream>>>(
        q_k, m_k, m_v, qkT, mkT, mvh);
    k_gemm_bt<true><<<dim3(L / 128, L / 128, NBATCH), 256, 0, stream>>>(
        qkT, mkT, (void*)pp, L, L, DK, 0.08838834764831845f);
    k_softmax<<<NBATCH * L, 256, 0, stream>>>(pp);
    hipMemcpyAsync(bounce, pp + 3 * LL, LL * sizeof(f16),
                   hipMemcpyDeviceToDevice, stream);
    k_gemm_bt<false><<<dim3(L / 128, DV / 128, NBATCH), 256, 0, stream>>>(
        mvh, pp, (void*)memOut, DV, L, L, 1.f / PSCALE);
    for (int b = 0; b < NBATCH; ++b) {
      const f16* src = (b == 3) ? bounce : (pp + (size_t)b * LL);
      k_tr_out<<<dim3(L / 64, L / 64), 256, 0, stream>>>(
          src, pOut + (size_t)b * LL, 1.f / PSCALE);
    }
  }
  (void)in_sizes; (void)n_in; (void)out_size; (void)ws_size;
}

// Round 13
// 165.270 us; speedup vs baseline: 2.5897x; 1.0151x over previous
//
#include <hip/hip_runtime.h>
#include <hip/hip_fp16.h>
#include <math.h>

typedef _Float16 f16;
typedef __attribute__((ext_vector_type(4))) _Float16 f16x4;
typedef __attribute__((ext_vector_type(8))) _Float16 f16x8;
typedef __attribute__((ext_vector_type(4))) float f32x4;

static constexpr int NBATCH = 4, DK = 128, DV = 512, L = 4096;
static constexpr float PSCALE = 256.f; // fallback path only

__device__ __forceinline__ void async16(const void* g, void* l) {
  __builtin_amdgcn_global_load_lds((const __attribute__((address_space(1))) void*)g,
                                   (__attribute__((address_space(3))) void*)l, 16, 0, 0);
}

// merged prep: z<4: transpose q_k batch z; z<8: transpose m_k batch z-4;
// z<12: convert m_v batch z-8 to f16. Fused path launches z=8 (transposes
// only — cvt rides inside k_qk); fallback launches z=12.
__global__ void k_prep(const float* __restrict__ qk, const float* __restrict__ mk,
                       const float* __restrict__ mv, f16* __restrict__ qkT,
                       f16* __restrict__ mkT, f16* __restrict__ mvh) {
  const int z = blockIdx.z;
  const int tx = threadIdx.x, ty = threadIdx.y, tid = ty * 32 + tx;
  if (z < 8) {
    __shared__ float tile[32][33];
    const size_t bs = (size_t)DK * L;
    const float* inb = (z < 4 ? qk : mk) + (size_t)(z & 3) * bs;
    f16* outb = (z < 4 ? qkT : mkT) + (size_t)(z & 3) * bs;
    const int c0 = blockIdx.x * 32, r0 = blockIdx.y * 32;
#pragma unroll
    for (int i = 0; i < 32; i += 8)
      tile[ty + i][tx] = inb[(size_t)(r0 + ty + i) * L + (c0 + tx)];
    __syncthreads();
#pragma unroll
    for (int i = 0; i < 32; i += 8)
      outb[(size_t)(c0 + ty + i) * DK + (r0 + tx)] = (f16)tile[tx][ty + i];
  } else {
    const int zb = z - 8;
    const int bid = blockIdx.x + 128 * blockIdx.y; // 0..511
    const size_t base = (size_t)zb * (DV * L / 4) + (size_t)bid * 1024;
    const float4* in4 = (const float4*)mv;
    f16x4* out4 = (f16x4*)mvh;
#pragma unroll
    for (int k = 0; k < 4; ++k) {
      float4 v = in4[base + tid + k * 256];
      f16x4 o;
      o.x = (f16)v.x; o.y = (f16)v.y; o.z = (f16)v.z; o.w = (f16)v.w;
      out4[base + tid + k * 256] = o;
    }
  }
}

// QK (R11-proven): e'[z][q][m] = exp(oscale*sum_k qkT[q][k]*mkT[m][k]) f16
// (normal stores - re-read by PV) + per-block row expsum partials.
// z==4 slice (1024 blocks): m_v f32->f16 convert (needed only by PV) —
// rides in QK's tail-wave bubbles instead of a serial prep phase.
__global__ __launch_bounds__(256, 2)
void k_qk(const f16* __restrict__ A, const f16* __restrict__ B,
          f16* __restrict__ C, float* __restrict__ aux,
          const float4* __restrict__ mv, f16x4* __restrict__ mvh,
          float oscale) {
  constexpr int BK = 64;
  const int M = L, N = L, K = DK;
  __shared__ __align__(16) f16 As[128 * BK];
  __shared__ __align__(16) f16 Bs[128 * BK];
  __shared__ float sums[128];
  const int z = blockIdx.z;
  if (z == 4) {
    // cvt slice: 1024 blocks x 256 thr x 8 float4 = NBATCH*DV*L elements
    const int bid = blockIdx.x + gridDim.x * blockIdx.y; // 0..1023
    const size_t base = (size_t)bid * 2048 + threadIdx.x;
#pragma unroll
    for (int k = 0; k < 8; ++k) {
      float4 v = mv[base + k * 256];
      f16x4 o;
      o.x = (f16)v.x; o.y = (f16)v.y; o.z = (f16)v.z; o.w = (f16)v.w;
      mvh[base + k * 256] = o;
    }
    return;
  }
  int bx = blockIdx.x, by = blockIdx.y;
  {
    const int n = gridDim.x * gridDim.y;
    const int id = bx + gridDim.x * by;
    const int id2 = (id & 7) * (n >> 3) + (id >> 3); // XCD chunk (n%8==0)
    bx = id2 % gridDim.x;
    by = id2 / gridDim.x;
  }
  const f16* Ab = A + (size_t)z * M * K;
  const f16* Bbp = B + (size_t)z * N * K;
  const int row0 = by * 128, col0 = bx * 128;
  const int tid = threadIdx.x, lane = tid & 63, wv = tid >> 6;
  const int wr = wv >> 1, wc = wv & 1;
  f32x4 acc[4][4] = {};
  const int srow = wv * 32 + (lane >> 3);
  const int sc = (lane & 7) ^ (lane >> 3); // source chunk pre-swizzle
  const f16* aSrc = Ab + (size_t)(row0 + srow) * K + sc * 8;
  const f16* bSrc = Bbp + (size_t)(col0 + srow) * K + sc * 8;
  f16* aDst = &As[(wv * 32) * BK];
  f16* bDst = &Bs[(wv * 32) * BK];

  for (int k0 = 0; k0 < K; k0 += BK) {
    __syncthreads();
#pragma unroll
    for (int j = 0; j < 4; ++j) {
      async16(aSrc + (size_t)(j * 8) * K + k0, aDst + (j * 8) * BK);
      async16(bSrc + (size_t)(j * 8) * K + k0, bDst + (j * 8) * BK);
    }
    __syncthreads();
#pragma unroll
    for (int kk = 0; kk < BK / 32; ++kk) {
      const int cx = ((kk * 4 + (lane >> 4)) ^ (lane & 7)) * 8;
      f16x8 av[4], bv[4];
#pragma unroll
      for (int i = 0; i < 4; ++i) {
        av[i] = *(const f16x8*)&As[(wr * 64 + i * 16 + (lane & 15)) * BK + cx];
        bv[i] = *(const f16x8*)&Bs[(wc * 64 + i * 16 + (lane & 15)) * BK + cx];
      }
#pragma unroll
      for (int i = 0; i < 4; ++i)
#pragma unroll
        for (int j = 0; j < 4; ++j)
          acc[i][j] = __builtin_amdgcn_mfma_f32_16x16x32_f16(av[i], bv[j], acc[i][j], 0, 0, 0);
    }
  }
  const size_t cb = (size_t)z * M * N;
  const int er = (lane >> 4) * 4, ec = lane & 15;
  float rp[16];
#pragma unroll
  for (int u = 0; u < 16; ++u) rp[u] = 0.f;
#pragma unroll
  for (int i = 0; i < 4; ++i) {
    const int r = row0 + wr * 64 + i * 16 + er;
#pragma unroll
    for (int j = 0; j < 4; ++j) {
      const int c = col0 + wc * 64 + j * 16 + ec;
#pragma unroll
      for (int t = 0; t < 4; ++t) {
        const float e = __expf(acc[i][j][t] * oscale);
        C[cb + (size_t)(r + t) * N + c] = (f16)e;
        rp[i * 4 + t] += e;
      }
    }
  }
#pragma unroll
  for (int u = 0; u < 16; ++u) {
    rp[u] += __shfl_xor(rp[u], 1);
    rp[u] += __shfl_xor(rp[u], 2);
    rp[u] += __shfl_xor(rp[u], 4);
    rp[u] += __shfl_xor(rp[u], 8);
  }
  if (wc == 1 && (lane & 15) == 0) {
#pragma unroll
    for (int i = 0; i < 4; ++i)
#pragma unroll
      for (int t = 0; t < 4; ++t)
        sums[wr * 64 + i * 16 + (lane >> 4) * 4 + t] = rp[i * 4 + t];
  }
  __syncthreads();
  if (wc == 0 && (lane & 15) == 0) {
#pragma unroll
    for (int i = 0; i < 4; ++i)
#pragma unroll
      for (int t = 0; t < 4; ++t) {
        const int r = wr * 64 + i * 16 + (lane >> 4) * 4 + t;
        aux[((size_t)z * gridDim.x + bx) * L + row0 + r] = rp[i * 4 + t] + sums[r];
      }
  }
}

// PV (R12-proven) + T5 setprio around the MFMA cluster.
// Double-buffer + raw barriers + store-aware counted vmcnt:
// vmcnt(8): tile-t loads drained, t+1 loads in flight.
// vmcnt(40) after a writeback step: the 32 p-stores also stay in flight.
__global__ __launch_bounds__(256, 2)
void k_pv(const f16* __restrict__ A, const f16* __restrict__ B,
          float* __restrict__ C, const float* __restrict__ partial,
          float* __restrict__ P) {
  constexpr int BK = 64;
  const int M = DV, N = L, K = L;
  __shared__ __align__(16) f16 As[2][128 * BK];
  __shared__ __align__(16) f16 Bs[2][128 * BK];
  __shared__ float sums[128];
  const int z = blockIdx.z;
  int bx = blockIdx.x, by = blockIdx.y;
  {
    const int n = gridDim.x * gridDim.y; // 128
    const int id = bx + gridDim.x * by;
    const int id2 = (id & 7) * (n >> 3) + (id >> 3); // XCD chunk
    by = id2 % gridDim.y;  // by-fastest: 4 v-blocks of one q-panel co-XCD
    bx = id2 / gridDim.y;
  }
  const f16* Ab = A + (size_t)z * M * K;
  const f16* Bbp = B + (size_t)z * N * K;
  const int row0 = by * 128, col0 = bx * 128;
  const int tid = threadIdx.x, lane = tid & 63, wv = tid >> 6;
  const int wr = wv >> 1, wc = wv & 1;
  f32x4 acc[4][4] = {};
  const int srow = wv * 32 + (lane >> 3);
  const int sc = (lane & 7) ^ (lane >> 3);
  const f16* aSrc = Ab + (size_t)(row0 + srow) * K + sc * 8;
  const f16* bSrc = Bbp + (size_t)(col0 + srow) * K + sc * 8;
  const int dOff = (wv * 32) * BK;

  // rowinv prologue from partials (bit-identical bx-ascending sum order)
  if (tid < 128) {
    const float* pp_ = partial + (size_t)z * 32 * L + col0 + tid;
    float s = 0.f;
#pragma unroll
    for (int b = 0; b < 32; ++b) s += pp_[(size_t)b * L];
    sums[tid] = 1.f / s;
  }
  __syncthreads();
  const float rv0 = sums[lane];
  const float rv1 = sums[64 + lane];

  const int nt = K / BK; // 64
  // prologue: stage tile 0 into buf 0 (8 loads/wave)
#pragma unroll
  for (int j = 0; j < 4; ++j) {
    async16(aSrc + (size_t)(j * 8) * K, &As[0][dOff + (j * 8) * BK]);
    async16(bSrc + (size_t)(j * 8) * K, &Bs[0][dOff + (j * 8) * BK]);
  }

  for (int t = 0; t < nt; ++t) {
    const int cur = t & 1;
    // WAR barrier (raw): all waves done reading buf[cur^1] at t-1
    __builtin_amdgcn_s_barrier();
    if (t + 1 < nt) {
      const int k0n = (t + 1) * BK;
#pragma unroll
      for (int j = 0; j < 4; ++j) {
        async16(aSrc + (size_t)(j * 8) * K + k0n, &As[cur ^ 1][dOff + (j * 8) * BK]);
        async16(bSrc + (size_t)(j * 8) * K + k0n, &Bs[cur ^ 1][dOff + (j * 8) * BK]);
      }
      if (t >= 1 && ((t - 1) >> 4) == by) {
        asm volatile("s_waitcnt vmcnt(40)" ::: "memory");
      } else {
        asm volatile("s_waitcnt vmcnt(8)" ::: "memory");
      }
    } else {
      asm volatile("s_waitcnt vmcnt(0)" ::: "memory");
    }
    __builtin_amdgcn_s_barrier(); // all waves have tile t resident
    __builtin_amdgcn_s_setprio(1);
#pragma unroll
    for (int kk = 0; kk < BK / 32; ++kk) {
      const int cx = ((kk * 4 + (lane >> 4)) ^ (lane & 7)) * 8;
      f16x8 av[4], bv[4];
#pragma unroll
      for (int i = 0; i < 4; ++i) {
        av[i] = *(const f16x8*)&As[cur][(wr * 64 + i * 16 + (lane & 15)) * BK + cx];
        bv[i] = *(const f16x8*)&Bs[cur][(wc * 64 + i * 16 + (lane & 15)) * BK + cx];
      }
#pragma unroll
      for (int i = 0; i < 4; ++i)
#pragma unroll
        for (int j = 0; j < 4; ++j)
          acc[i][j] = __builtin_amdgcn_mfma_f32_16x16x32_f16(av[i], bv[j], acc[i][j], 0, 0, 0);
    }
    __builtin_amdgcn_s_setprio(0);
    // fused p-writeback from LDS B-tile (nt stores; drained lazily above)
    if ((t >> 4) == by) {
      const int k0 = t * BK;
#pragma unroll
      for (int h = 0; h < 2; ++h) {
        const int cc = wv * 2 + h; // this wave's 8-m chunk (0..7)
#pragma unroll
        for (int qh = 0; qh < 2; ++qh) {
          const int q = qh * 64 + lane;
          const f16x8 ev = *(const f16x8*)&Bs[cur][q * BK + ((cc ^ (q & 7)) * 8)];
          const float rv = qh ? rv1 : rv0;
          float* pr = P + (size_t)z * L * L + (size_t)(k0 + cc * 8) * L + col0 + q;
#pragma unroll
          for (int j = 0; j < 8; ++j)
            __builtin_nontemporal_store((float)ev[j] * rv, pr + (size_t)j * L);
        }
      }
    }
  }
  // mem epilogue: col = lane&15, row = (lane>>4)*4 + t (nt, never re-read)
  const size_t cb = (size_t)z * M * N;
  const int er = (lane >> 4) * 4, ec = lane & 15;
  float rvj[4];
#pragma unroll
  for (int j = 0; j < 4; ++j) rvj[j] = sums[wc * 64 + j * 16 + ec];
#pragma unroll
  for (int i = 0; i < 4; ++i) {
    const int r = row0 + wr * 64 + i * 16 + er;
#pragma unroll
    for (int j = 0; j < 4; ++j) {
      const int c = col0 + wc * 64 + j * 16 + ec;
#pragma unroll
      for (int t = 0; t < 4; ++t)
        __builtin_nontemporal_store(acc[i][j][t] * rvj[j],
                                    &C[cb + (size_t)(r + t) * N + c]);
    }
  }
}

// ---------------- fallback-path kernels (proven round-1) ----------------
template<bool OUT_F16>
__global__ __launch_bounds__(256, 2)
void k_gemm_bt(const f16* __restrict__ A, const f16* __restrict__ B,
               void* __restrict__ C, int M, int N, int K, float oscale) {
  constexpr int BK = 64;
  __shared__ __align__(16) f16 As[128 * BK];
  __shared__ __align__(16) f16 Bs[128 * BK];
  const int z = blockIdx.z;
  const f16* Ab = A + (size_t)z * M * K;
  const f16* Bbp = B + (size_t)z * N * K;
  const int row0 = blockIdx.y * 128, col0 = blockIdx.x * 128;
  const int tid = threadIdx.x, lane = tid & 63, wv = tid >> 6;
  const int wr = wv >> 1, wc = wv & 1;
  f32x4 acc[4][4] = {};
  const int srow = wv * 32 + (lane >> 3);
  const int sc = (lane & 7) ^ (lane >> 3);
  const f16* aSrc = Ab + (size_t)(row0 + srow) * K + sc * 8;
  const f16* bSrc = Bbp + (size_t)(col0 + srow) * K + sc * 8;
  f16* aDst = &As[(wv * 32) * BK];
  f16* bDst = &Bs[(wv * 32) * BK];
  for (int k0 = 0; k0 < K; k0 += BK) {
    __syncthreads();
#pragma unroll
    for (int j = 0; j < 4; ++j) {
      async16(aSrc + (size_t)(j * 8) * K + k0, aDst + (j * 8) * BK);
      async16(bSrc + (size_t)(j * 8) * K + k0, bDst + (j * 8) * BK);
    }
    __syncthreads();
#pragma unroll
    for (int kk = 0; kk < BK / 32; ++kk) {
      const int cx = ((kk * 4 + (lane >> 4)) ^ (lane & 7)) * 8;
      f16x8 av[4], bv[4];
#pragma unroll
      for (int i = 0; i < 4; ++i) {
        av[i] = *(const f16x8*)&As[(wr * 64 + i * 16 + (lane & 15)) * BK + cx];
        bv[i] = *(const f16x8*)&Bs[(wc * 64 + i * 16 + (lane & 15)) * BK + cx];
      }
#pragma unroll
      for (int i = 0; i < 4; ++i)
#pragma unroll
        for (int j = 0; j < 4; ++j)
          acc[i][j] = __builtin_amdgcn_mfma_f32_16x16x32_f16(av[i], bv[j], acc[i][j], 0, 0, 0);
    }
  }
  const size_t cb = (size_t)z * M * N;
  const int er = (lane >> 4) * 4, ec = lane & 15;
#pragma unroll
  for (int i = 0; i < 4; ++i) {
    const int r = row0 + wr * 64 + i * 16 + er;
#pragma unroll
    for (int j = 0; j < 4; ++j) {
      const int c = col0 + wc * 64 + j * 16 + ec;
#pragma unroll
      for (int t = 0; t < 4; ++t) {
        const float v = acc[i][j][t] * oscale;
        if (OUT_F16) ((f16*)C)[cb + (size_t)(r + t) * N + c] = (f16)v;
        else        ((float*)C)[cb + (size_t)(r + t) * N + c] = v;
      }
    }
  }
}

__global__ __launch_bounds__(256)
void k_softmax(f16* __restrict__ S) {
  const size_t rowbase = (size_t)blockIdx.x * L;
  const int tid = threadIdx.x, ln = tid & 63, wv = tid >> 6;
  f16* p = S + rowbase + tid * 16;
  f16x8 v0 = *(const f16x8*)p;
  f16x8 v1 = *(const f16x8*)(p + 8);
  float x[16];
#pragma unroll
  for (int j = 0; j < 8; ++j) { x[j] = (float)v0[j]; x[8 + j] = (float)v1[j]; }
  float m = -3.0e38f;
#pragma unroll
  for (int j = 0; j < 16; ++j) m = fmaxf(m, x[j]);
#pragma unroll
  for (int off = 1; off < 64; off <<= 1) m = fmaxf(m, __shfl_xor(m, off));
  __shared__ float redm[4], reds[4];
  if (ln == 0) redm[wv] = m;
  __syncthreads();
  m = fmaxf(fmaxf(redm[0], redm[1]), fmaxf(redm[2], redm[3]));
  float s = 0.f;
#pragma unroll
  for (int j = 0; j < 16; ++j) { x[j] = __expf(x[j] - m); s += x[j]; }
#pragma unroll
  for (int off = 1; off < 64; off <<= 1) s += __shfl_xor(s, off);
  if (ln == 0) reds[wv] = s;
  __syncthreads();
  s = (reds[0] + reds[1]) + (reds[2] + reds[3]);
  const float k = PSCALE / s;
#pragma unroll
  for (int j = 0; j < 8; ++j) { v0[j] = (f16)(x[j] * k); v1[j] = (f16)(x[8 + j] * k); }
  *(f16x8*)p = v0;
  *(f16x8*)(p + 8) = v1;
}

__global__ __launch_bounds__(256)
void k_tr_out(const f16* __restrict__ src, float* __restrict__ dst, float scale) {
  __shared__ float tile[64][65];
  const int m0 = blockIdx.x * 64, q0 = blockIdx.y * 64;
  const int tid = threadIdx.x;
  const int r = tid >> 2, c4 = (tid & 3) * 16;
  const f16* sp = src + (size_t)(q0 + r) * L + m0 + c4;
  f16x8 a = *(const f16x8*)sp;
  f16x8 b = *(const f16x8*)(sp + 8);
#pragma unroll
  for (int j = 0; j < 8; ++j) {
    tile[c4 + j][r] = (float)a[j] * scale;
    tile[c4 + 8 + j][r] = (float)b[j] * scale;
  }
  __syncthreads();
  float* dp = dst + (size_t)(m0 + r) * L + q0 + c4;
#pragma unroll
  for (int g = 0; g < 4; ++g) {
    float4 w;
    w.x = tile[r][c4 + 4 * g + 0];
    w.y = tile[r][c4 + 4 * g + 1];
    w.z = tile[r][c4 + 4 * g + 2];
    w.w = tile[r][c4 + 4 * g + 3];
    *(float4*)(dp + 4 * g) = w;
  }
}

extern "C" void kernel_launch(void* const* d_in, const int* in_sizes, int n_in,
                              void* d_out, int out_size, void* d_ws, size_t ws_size,
                              hipStream_t stream) {
  const float* m_k = (const float*)d_in[0];
  const float* m_v = (const float*)d_in[1];
  const float* q_k = (const float*)d_in[2];
  char* ws = (char*)d_ws;
  float* memOut = (float*)d_out;                  // [B][Dv][L]
  float* pOut = memOut + (size_t)NBATCH * DV * L; // [B][L][L] f32
  const size_t LL = (size_t)L * L;

  const bool fused = ws_size >= ((size_t)160 << 20);
  if (fused) {
    f16* pp = (f16*)ws;                                   // 128 MiB e'
    float* partial = (float*)(ws + ((size_t)128 << 20));  // 2 MiB
    f16* qkT = (f16*)(ws + ((size_t)131 << 20));          // 4 MiB
    f16* mkT = (f16*)(ws + ((size_t)135 << 20));          // 4 MiB
    f16* mvh = (f16*)(ws + ((size_t)139 << 20));          // 16 MiB
    // prep: transposes only (z=8); mvh convert rides in k_qk's z=4 slice
    k_prep<<<dim3(L / 32, DK / 32, 8), dim3(32, 8), 0, stream>>>(
        q_k, m_k, m_v, qkT, mkT, mvh);
    k_qk<<<dim3(L / 128, L / 128, NBATCH + 1), 256, 0, stream>>>(
        qkT, mkT, pp, partial, (const float4*)m_v, (f16x4*)mvh,
        0.08838834764831845f);
    k_pv<<<dim3(L / 128, DV / 128, NBATCH), 256, 0, stream>>>(
        mvh, pp, memOut, partial, pOut);
  } else {
    // proven round-1 path
    f16* bounce = (f16*)ws;
    f16* qkT = (f16*)(ws + ((size_t)32 << 20));
    f16* mkT = (f16*)(ws + ((size_t)36 << 20));
    f16* mvh = (f16*)(ws + ((size_t)40 << 20));
    f16* pp = (f16*)(pOut + NBATCH * LL / 2);
    k_prep<<<dim3(L / 32, DK / 32, 12), dim3(32, 8), 0, stream>>>(
        q_k, m_k, m_v, qkT, mkT, mvh);
    k_gemm_bt<true><<<dim3(L / 128, L / 128, NBATCH), 256, 0, stream>>>(
        qkT, mkT, (void*)pp, L, L, DK, 0.08838834764831845f);
    k_softmax<<<NBATCH * L, 256, 0, stream>>>(pp);
    hipMemcpyAsync(bounce, pp + 3 * LL, LL * sizeof(f16),
                   hipMemcpyDeviceToDevice, stream);
    k_gemm_bt<false><<<dim3(L / 128, DV / 128, NBATCH), 256, 0, stream>>>(
        mvh, pp, (void*)memOut, DV, L, L, 1.f / PSCALE);
    for (int b = 0; b < NBATCH; ++b) {
      const f16* src = (b == 3) ? bounce : (pp + (size_t)b * LL);
      k_tr_out<<<dim3(L / 64, L / 64), 256, 0, stream>>>(
          src, pOut + (size_t)b * LL, 1.f / PSCALE);
    }
  }
  (void)in_sizes; (void)n_in; (void)out_size; (void)ws_size;
}